// Round 1
// baseline (90.385 us; speedup 1.0000x reference)
//
#include <hip/hip_runtime.h>

#define B_      16384
#define NS      8
#define NSEQ    2
#define ND      4
#define VOCAB   100000
#define D_      64
#define L_      50
#define OUT_COLS ((NS + NSEQ) * D_ + ND)   // 644

// One wave (64 lanes) per batch row; lane == embedding dim.
// Every table gather is a fully coalesced 256B wave transaction.
__global__ __launch_bounds__(256) void embed_kernel(
    const int*   __restrict__ sparse_ids,   // [B, NS]
    const int*   __restrict__ seq_ids,      // [B, NSEQ, L]
    const float* __restrict__ dense,        // [B, ND]
    const float* __restrict__ tbl_sparse,   // [NS, VOCAB, D]
    const float* __restrict__ tbl_seq,      // [NSEQ, VOCAB, D]
    float*       __restrict__ out)          // [B, OUT_COLS]
{
    const int lane = threadIdx.x & 63;
    const int b    = (blockIdx.x * blockDim.x + threadIdx.x) >> 6;
    if (b >= B_) return;

    float* orow = out + (size_t)b * OUT_COLS;

    // ---- sparse gathers: 8 tables, one id each ----
    {
        const int* sid = sparse_ids + b * NS;
        int my_sid = (lane < NS) ? sid[lane] : 0;   // coalesced 32B load
        #pragma unroll
        for (int t = 0; t < NS; ++t) {
            int id = __shfl(my_sid, t);             // wave-uniform broadcast
            float v = tbl_sparse[((size_t)t * VOCAB + id) * D_ + lane];
            orow[t * D_ + lane] = v;
        }
    }

    // ---- sequence pooling: feature 0 = sum, feature 1 = masked mean ----
    #pragma unroll
    for (int f = 0; f < NSEQ; ++f) {
        const int* qid = seq_ids + ((size_t)b * NSEQ + f) * L_;
        int my_qid = (lane < L_) ? qid[lane] : -1;  // coalesced 200B load
        const float* tb = tbl_seq + (size_t)f * VOCAB * D_;
        float acc = 0.0f;
        int   cnt = 0;
        #pragma unroll
        for (int l = 0; l < L_; ++l) {
            int id = __shfl(my_qid, l);             // wave-uniform
            if (id != -1) {                         // uniform branch, no divergence
                acc += tb[(size_t)id * D_ + lane];
                ++cnt;
            }
        }
        if (f == 1) acc = acc / ((float)cnt + 1e-16f);
        orow[(NS + f) * D_ + lane] = acc;
    }

    // ---- dense passthrough (4 floats) ----
    if (lane < ND) orow[(NS + NSEQ) * D_ + lane] = dense[b * ND + lane];
}

extern "C" void kernel_launch(void* const* d_in, const int* in_sizes, int n_in,
                              void* d_out, int out_size, void* d_ws, size_t ws_size,
                              hipStream_t stream) {
    const int*   sparse_ids = (const int*)  d_in[0];
    const int*   seq_ids    = (const int*)  d_in[1];
    const float* dense      = (const float*)d_in[2];
    const float* tbl_sparse = (const float*)d_in[3];
    const float* tbl_seq    = (const float*)d_in[4];
    float*       out        = (float*)d_out;

    // 4 waves (rows) per 256-thread block
    const int rows_per_block = 256 / 64;
    dim3 grid(B_ / rows_per_block);
    dim3 block(256);
    embed_kernel<<<grid, block, 0, stream>>>(sparse_ids, seq_ids, dense,
                                             tbl_sparse, tbl_seq, out);
}

// Round 2
// 73.785 us; speedup vs baseline: 1.2250x; 1.2250x over previous
//
#include <hip/hip_runtime.h>

#define B_      16384
#define NS      8
#define NSEQ    2
#define ND      4
#define VOCAB   100000
#define D_      64
#define L_      50
#define OUT_COLS ((NS + NSEQ) * D_ + ND)   // 644

// One wave (64 lanes) per batch row.
// Layout: 4 lane-groups of 16 lanes; each lane holds float4 -> a 16-lane group
// covers one 256B embedding row, so one wave-instruction gathers 4 rows at once.
// All seq gathers for a group are staged into a register array (compile-time
// indexed, fully unrolled) to keep ~13 loads in flight per wave.
__global__ __launch_bounds__(256) void embed_kernel(
    const int*   __restrict__ sparse_ids,   // [B, NS]
    const int*   __restrict__ seq_ids,      // [B, NSEQ, L]
    const float* __restrict__ dense,        // [B, ND]
    const float* __restrict__ tbl_sparse,   // [NS, VOCAB, D]
    const float* __restrict__ tbl_seq,      // [NSEQ, VOCAB, D]
    float*       __restrict__ out)          // [B, OUT_COLS]
{
    const int lane = threadIdx.x & 63;
    const int g    = lane >> 4;       // lane-group 0..3
    const int s    = lane & 15;       // sublane: float4 slot within the row
    const int b    = (blockIdx.x * blockDim.x + threadIdx.x) >> 6;
    if (b >= B_) return;

    float* orow = out + (size_t)b * OUT_COLS;

    // ---- sparse gathers: 8 tables; group g handles tables g and g+4 ----
    {
        int my_sid = (lane < NS) ? sparse_ids[b * NS + lane] : 0;
        const float4* ts4 = (const float4*)tbl_sparse;
        float4 sv[2];
        #pragma unroll
        for (int i = 0; i < 2; ++i) {
            int t  = g + 4 * i;
            int id = __shfl(my_sid, t);
            sv[i] = ts4[((size_t)t * VOCAB + id) * 16 + s];
        }
        #pragma unroll
        for (int i = 0; i < 2; ++i) {
            int t = g + 4 * i;
            *(float4*)(orow + t * D_ + s * 4) = sv[i];  // wave writes 1KB contiguous
        }
    }

    // ---- sequence pooling: f0 = sum, f1 = masked mean ----
    constexpr int NIT = (L_ + 3) / 4;   // 13 ids per group
    #pragma unroll
    for (int f = 0; f < NSEQ; ++f) {
        int my_qid = (lane < L_) ? seq_ids[((size_t)b * NSEQ + f) * L_ + lane] : -1;
        const float4* tq4 = (const float4*)(tbl_seq + (size_t)f * VOCAB * D_);

        // broadcast this group's ids (j = 4k + g; max j = 51 < 64, lanes >= 50 hold -1)
        int raw[NIT];
        #pragma unroll
        for (int k = 0; k < NIT; ++k)
            raw[k] = __shfl(my_qid, 4 * k + g);

        // batched gathers: all 13 loads issued before any accumulate
        float4 vals[NIT];
        #pragma unroll
        for (int k = 0; k < NIT; ++k) {
            int id = (raw[k] != -1) ? raw[k] : 0;   // safe address for padded slots
            vals[k] = tq4[(size_t)id * 16 + s];
        }

        float4 acc = make_float4(0.f, 0.f, 0.f, 0.f);
        float  cnt = 0.f;
        #pragma unroll
        for (int k = 0; k < NIT; ++k) {
            float m = (raw[k] != -1) ? 1.f : 0.f;
            acc.x += vals[k].x * m;
            acc.y += vals[k].y * m;
            acc.z += vals[k].z * m;
            acc.w += vals[k].w * m;
            cnt   += m;
        }

        // reduce the 4 lane-groups (bits 4,5 of lane)
        #pragma unroll
        for (int off = 16; off < 64; off <<= 1) {
            acc.x += __shfl_xor(acc.x, off);
            acc.y += __shfl_xor(acc.y, off);
            acc.z += __shfl_xor(acc.z, off);
            acc.w += __shfl_xor(acc.w, off);
            cnt   += __shfl_xor(cnt,   off);
        }

        if (f == 1) {
            float inv = 1.f / (cnt + 1e-16f);
            acc.x *= inv; acc.y *= inv; acc.z *= inv; acc.w *= inv;
        }
        if (g == 0)
            *(float4*)(orow + (NS + f) * D_ + s * 4) = acc;  // 256B coalesced
    }

    // ---- dense passthrough (4 floats, 16B aligned: 644*4 and 640*4 are /16) ----
    if (lane == 0) {
        float4 dv = ((const float4*)dense)[b];
        *(float4*)(orow + (NS + NSEQ) * D_) = dv;
    }
}

extern "C" void kernel_launch(void* const* d_in, const int* in_sizes, int n_in,
                              void* d_out, int out_size, void* d_ws, size_t ws_size,
                              hipStream_t stream) {
    const int*   sparse_ids = (const int*)  d_in[0];
    const int*   seq_ids    = (const int*)  d_in[1];
    const float* dense      = (const float*)d_in[2];
    const float* tbl_sparse = (const float*)d_in[3];
    const float* tbl_seq    = (const float*)d_in[4];
    float*       out        = (float*)d_out;

    const int rows_per_block = 256 / 64;   // 4 waves per block, 1 row per wave
    dim3 grid(B_ / rows_per_block);
    dim3 block(256);
    embed_kernel<<<grid, block, 0, stream>>>(sparse_ids, seq_ids, dense,
                                             tbl_sparse, tbl_seq, out);
}

// Round 3
// 71.650 us; speedup vs baseline: 1.2615x; 1.0298x over previous
//
#include <hip/hip_runtime.h>

#define B_      16384
#define NS      8
#define NSEQ    2
#define ND      4
#define VOCAB   100000
#define D_      64
#define L_      50
#define OUT_COLS ((NS + NSEQ) * D_ + ND)   // 644

// One wave (64 lanes) per batch row.
// 4 lane-groups x 16 lanes x float4 -> one wave-instruction gathers 4 rows.
// ALL 28 gathers (2 sparse + 13+13 seq) are issued before any accumulation;
// padding masks are packed into bit-words so only the float4 payloads stay
// live across the load batch (keeps VGPR ~150, 8 waves/CU, 28KB in flight/CU).
__global__ __launch_bounds__(256, 2) void embed_kernel(
    const int*   __restrict__ sparse_ids,   // [B, NS]
    const int*   __restrict__ seq_ids,      // [B, NSEQ, L]
    const float* __restrict__ dense,        // [B, ND]
    const float* __restrict__ tbl_sparse,   // [NS, VOCAB, D]
    const float* __restrict__ tbl_seq,      // [NSEQ, VOCAB, D]
    float*       __restrict__ out)          // [B, OUT_COLS]
{
    const int lane = threadIdx.x & 63;
    const int g    = lane >> 4;       // lane-group 0..3
    const int s    = lane & 15;       // float4 slot within the 64-float row
    const int b    = (blockIdx.x * blockDim.x + threadIdx.x) >> 6;
    if (b >= B_) return;

    // ---- coalesced id loads (issued first, everything depends on them) ----
    const int* qbase = seq_ids + (size_t)b * NSEQ * L_;
    int my_sid = (lane < NS) ? sparse_ids[b * NS + lane] : 0;
    int my_q0  = (lane < L_) ? qbase[lane]       : -1;
    int my_q1  = (lane < L_) ? qbase[L_ + lane]  : -1;

    // ---- issue ALL gathers back-to-back ----
    const float4* ts4 = (const float4*)tbl_sparse;
    const float4* tq0 = (const float4*)tbl_seq;
    const float4* tq1 = (const float4*)(tbl_seq + (size_t)VOCAB * D_);

    int sid0 = __shfl(my_sid, g);
    int sid1 = __shfl(my_sid, g + 4);
    float4 sv0 = ts4[((size_t)g       * VOCAB + sid0) * 16 + s];
    float4 sv1 = ts4[((size_t)(g + 4) * VOCAB + sid1) * 16 + s];

    constexpr int NIT = (L_ + 3) / 4;   // 13 ids per lane-group
    unsigned m0 = 0, m1 = 0;
    float4 v0[NIT], v1[NIT];
    #pragma unroll
    for (int k = 0; k < NIT; ++k) {
        int r = __shfl(my_q0, 4 * k + g);           // j = 4k+g (<52; >=50 hold -1)
        m0 |= (r != -1 ? 1u : 0u) << k;
        int id = (r != -1) ? r : 0;
        v0[k] = tq0[(size_t)id * 16 + s];
    }
    #pragma unroll
    for (int k = 0; k < NIT; ++k) {
        int r = __shfl(my_q1, 4 * k + g);
        m1 |= (r != -1 ? 1u : 0u) << k;
        int id = (r != -1) ? r : 0;
        v1[k] = tq1[(size_t)id * 16 + s];
    }

    // ---- accumulate (masked) ----
    float4 a0 = make_float4(0.f, 0.f, 0.f, 0.f);
    float4 a1 = make_float4(0.f, 0.f, 0.f, 0.f);
    #pragma unroll
    for (int k = 0; k < NIT; ++k) {
        float m = (float)((m0 >> k) & 1u);
        a0.x += v0[k].x * m; a0.y += v0[k].y * m;
        a0.z += v0[k].z * m; a0.w += v0[k].w * m;
    }
    #pragma unroll
    for (int k = 0; k < NIT; ++k) {
        float m = (float)((m1 >> k) & 1u);
        a1.x += v1[k].x * m; a1.y += v1[k].y * m;
        a1.z += v1[k].z * m; a1.w += v1[k].w * m;
    }
    float c1 = (float)__popc(m1);

    // ---- reduce the 4 lane-groups (lane bits 4,5) ----
    #pragma unroll
    for (int off = 16; off < 64; off <<= 1) {
        a0.x += __shfl_xor(a0.x, off); a0.y += __shfl_xor(a0.y, off);
        a0.z += __shfl_xor(a0.z, off); a0.w += __shfl_xor(a0.w, off);
        a1.x += __shfl_xor(a1.x, off); a1.y += __shfl_xor(a1.y, off);
        a1.z += __shfl_xor(a1.z, off); a1.w += __shfl_xor(a1.w, off);
        c1   += __shfl_xor(c1,   off);
    }
    {
        float inv = 1.f / (c1 + 1e-16f);
        a1.x *= inv; a1.y *= inv; a1.z *= inv; a1.w *= inv;
    }

    // ---- stores, all at the end ----
    float* orow = out + (size_t)b * OUT_COLS;
    *(float4*)(orow + g       * D_ + s * 4) = sv0;   // wave: 1KB contiguous
    *(float4*)(orow + (g + 4) * D_ + s * 4) = sv1;
    if (g == 0) {
        *(float4*)(orow + NS * D_ + s * 4)       = a0;
        *(float4*)(orow + (NS + 1) * D_ + s * 4) = a1;
    }
    if (lane == 0) {
        float4 dv = ((const float4*)dense)[b];
        *(float4*)(orow + (NS + NSEQ) * D_) = dv;
    }
}

extern "C" void kernel_launch(void* const* d_in, const int* in_sizes, int n_in,
                              void* d_out, int out_size, void* d_ws, size_t ws_size,
                              hipStream_t stream) {
    const int*   sparse_ids = (const int*)  d_in[0];
    const int*   seq_ids    = (const int*)  d_in[1];
    const float* dense      = (const float*)d_in[2];
    const float* tbl_sparse = (const float*)d_in[3];
    const float* tbl_seq    = (const float*)d_in[4];
    float*       out        = (float*)d_out;

    const int rows_per_block = 256 / 64;   // 4 waves per block, 1 row per wave
    dim3 grid(B_ / rows_per_block);
    dim3 block(256);
    embed_kernel<<<grid, block, 0, stream>>>(sparse_ids, seq_ids, dense,
                                             tbl_sparse, tbl_seq, out);
}